// Round 2
// baseline (82.511 us; speedup 1.0000x reference)
//
#include <hip/hip_runtime.h>

// SignatureScoringLoss — round 15: identical compute to r14 (81.3 µs verified),
// output store fixed to bf16 (this harness's out dtype is bf16: test reads
// uint16<<16 as float). Computation was already correct — the float32 store's
// low 16 bits decoded as bf16 ~0, giving the exact absmax error of 1.0.
//  - Mm stored as (a, nb) float2 coefficient pairs (computed in Gram phase);
//    boundary pair (1,-1) == m=0 keeps the virtual-tile identity exact.
//  - PDE lane handoff via v_mov_dpp wave_shr:1 with old=1.0 (K[0][*]=1 free).
//  - Gram fully unrolled; first 8 coefficient pairs loaded mid-Gram.
// Weights calibrated r2/r3: XX 1/480 (upper triangle), XY -1/32.

#define SEQ   65
#define DIMS  8
#define MPOP  16
#define NBATCH 4
#define NPAIR_XX 120
#define NPAIRS (NBATCH*(NPAIR_XX + MPOP))   // 544
#define CST 67        // (a,nb) pairs per row; odd stride -> conflict-free b64

__device__ __forceinline__ float wave_shr1_one(float x) { // lane I <- I-1; lane0 <- 1.0
    int xi = __builtin_bit_cast(int, x);
    int r  = __builtin_amdgcn_update_dpp(0x3f800000, xi, 0x138, 0xF, 0xF, false);
    return __builtin_bit_cast(float, r);
}
__device__ __forceinline__ float wave_shl1(float x) {     // lane I <- I+1
    int xi = __builtin_bit_cast(int, x);
    int r  = __builtin_amdgcn_update_dpp(xi, xi, 0x130, 0xF, 0xF, false);
    return __builtin_bit_cast(float, r);
}
__device__ __forceinline__ float2 ldc(const float2* b, int i) {
    return b[i < 0 ? 0 : i];          // clamp ramp-in to row's boundary pair
}

struct PS { float l0,l1,l2,l3,b0,b1,b2,b3,cn; };

__device__ __forceinline__ void pde_step(PS& s, float2 co) {
    const float a  = co.x;
    const float nb = co.y;
    float t0 = wave_shr1_one(s.b0);
    float t1 = wave_shr1_one(s.b1);
    float t2 = wave_shr1_one(s.b2);
    float t3 = wave_shr1_one(s.b3);
    float c = s.cn; s.cn = t3;
    float u0 = a*t0 + nb*c;
    float u1 = a*t1 + nb*t0;
    float u2 = a*t2 + nb*t1;
    float u3 = a*t3 + nb*t2;
    float q1 = a*s.l0 + u0;
    float q2 = a*q1 + u1;
    float q3 = a*q2 + u2;
    float q4 = a*q3 + u3;
    u0 = a*q1 + nb*s.l0; u1 = a*q2 + nb*q1; u2 = a*q3 + nb*q2; u3 = a*q4 + nb*q3;
    float r1 = a*s.l1 + u0;
    float r2 = a*r1 + u1;
    float r3 = a*r2 + u2;
    float r4 = a*r3 + u3;
    u0 = a*r1 + nb*s.l1; u1 = a*r2 + nb*r1; u2 = a*r3 + nb*r2; u3 = a*r4 + nb*r3;
    float w1 = a*s.l2 + u0;
    float w2 = a*w1 + u1;
    float w3 = a*w2 + u2;
    float w4 = a*w3 + u3;
    u0 = a*w1 + nb*s.l2; u1 = a*w2 + nb*w1; u2 = a*w3 + nb*w2; u3 = a*w4 + nb*w3;
    float v1 = a*s.l3 + u0;
    float v2 = a*v1 + u1;
    float v3 = a*v2 + u2;
    float v4 = a*v3 + u3;
    s.b0=v1; s.b1=v2; s.b2=v3; s.b3=v4;
    s.l0=q4; s.l1=r4; s.l2=w4; s.l3=v4;
}

__global__ __launch_bounds__(64, 1) void sigker_kernel(
    const float* __restrict__ gen,    // (B,16,8,65)
    const float* __restrict__ realp,  // (B,8,65)
    float* __restrict__ ws)           // 544 partials
{
    __shared__ __align__(16) float YsF[SEQ * DIMS];   // y paths [s][d]
    __shared__ float2 YnR[SEQ];                       // (|y_t|^2, R64[t])
    __shared__ float2 CmL[64 * CST];                  // (a, nb) per coarse cell

    const int tid = threadIdx.x;      // one wave
    const int I   = tid;
    const int bid = blockIdx.x;

    // ---- decode pair (unordered XX upper triangle + XY) ----
    int b, ii, jj; bool cross;
    if (bid < NBATCH * NPAIR_XX) {
        b = bid / NPAIR_XX;
        int p = bid % NPAIR_XX;
        int i = 0, acc = 0;
        while (p >= acc + (MPOP - 1 - i)) { acc += (MPOP - 1 - i); ++i; }
        ii = i; jj = i + 1 + (p - acc); cross = false;
    } else {
        int t = bid - NBATCH * NPAIR_XX;
        b = t / MPOP; ii = t % MPOP; jj = 0; cross = true;
    }

    const float* Xg = gen + (size_t)(b * MPOP + ii) * (DIMS * SEQ);
    const float* Yg = cross ? (realp + (size_t)b * (DIMS * SEQ))
                            : (gen + (size_t)(b * MPOP + jj) * (DIMS * SEQ));

    // ---- global loads first (overlap latency with LDS setup) ----
    float x0[DIMS], x64[DIMS];
    #pragma unroll
    for (int d = 0; d < DIMS; ++d) {
        x0[d]  = Xg[d * SEQ + I];
        x64[d] = Xg[d * SEQ + 64];    // uniform addr -> broadcast
    }
    CmL[CST * I] = make_float2(1.0f, -1.0f);   // boundary pair (m=0)
    for (int f = tid; f < SEQ * DIMS; f += 64) {
        int d = f / SEQ, s = f - d * SEQ;
        YsF[s * DIMS + d] = Yg[f];
    }
    float xn0 = 0.f, xn64 = 0.f;
    #pragma unroll
    for (int d = 0; d < DIMS; ++d) {
        xn0  += x0[d]  * x0[d];
        xn64 += x64[d] * x64[d];
    }
    __syncthreads();

    // ---- pre-pass: (|y_t|^2, e-row for x_64) ----
    for (int t = tid; t < SEQ; t += 64) {
        const float4* yv = (const float4*)&YsF[t * DIMS];
        float4 ya = yv[0], yb = yv[1];
        float yn  = ya.x*ya.x + ya.y*ya.y + ya.z*ya.z + ya.w*ya.w
                  + yb.x*yb.x + yb.y*yb.y + yb.z*yb.z + yb.w*yb.w;
        float dot = x64[0]*ya.x + x64[1]*ya.y + x64[2]*ya.z + x64[3]*ya.w
                  + x64[4]*yb.x + x64[5]*yb.y + x64[6]*yb.z + x64[7]*yb.w;
        YnR[t] = make_float2(yn, __expf(2.f*dot - xn64 - yn));
    }
    __syncthreads();

    // ---- Gram + coefficients (fully unrolled), early mA prefetch ----
    float2* crow = &CmL[CST * I];     // real pairs at idx 1..64
    const int ib = 1 - I;             // PDE pair idx for step D = ib + D
    float2 mA[8], mB[8];
    float ep, enp;
    {
        const float4* yv = (const float4*)&YsF[0];
        float4 ya = yv[0], yb = yv[1];
        float dot = x0[0]*ya.x + x0[1]*ya.y + x0[2]*ya.z + x0[3]*ya.w
                  + x0[4]*yb.x + x0[5]*yb.y + x0[6]*yb.z + x0[7]*yb.w;
        float2 yr = YnR[0];
        float e  = __expf(2.f*dot - xn0 - yr.x);
        float en = wave_shl1(e);
        en = (I == 63) ? yr.y : en;
        ep = e; enp = en;
    }
    #pragma unroll
    for (int t = 1; t < SEQ; ++t) {
        const float4* yv = (const float4*)&YsF[t * DIMS];
        float4 ya = yv[0], yb = yv[1];
        float dot = x0[0]*ya.x + x0[1]*ya.y + x0[2]*ya.z + x0[3]*ya.w
                  + x0[4]*yb.x + x0[5]*yb.y + x0[6]*yb.z + x0[7]*yb.w;
        float2 yr = YnR[t];
        float e  = __expf(2.f*dot - xn0 - yr.x);
        float en = wave_shl1(e);
        en = (I == 63) ? yr.y : en;
        // inc[I][t-1] = G[I+1][t] + G[I][t-1] - G[I+1][t-1] - G[I][t]
        float m   = ((en - enp) + (ep - e)) * (1.0f / 16.0f);
        float q12 = m * m * (1.0f / 12.0f);
        float a   = (1.0f + q12) + 0.5f * m;
        float nb  = q12 - 1.0f;
        crow[t] = make_float2(a, nb);
        ep = e; enp = en;
        if (t == 8) {
            // lane I's PDE warm-up pairs are crow[clamp(ib..ib+7)], max idx 8:
            // all written by now (own-row, wave-ordered DS). Load early so
            // their latency hides under the remaining 56 Gram iterations.
            #pragma unroll
            for (int k = 0; k < 8; ++k) mA[k] = ldc(crow, ib + k);
        }
    }
    // crow written+read only by lane I (wave-ordered DS): no barrier.

    // ---- PDE: 127 steps, A/B ping-pong 8-deep coefficient prefetch ----
    PS S = {1,1,1,1, 1,1,1,1, 1};

    for (int g = 0; g < 7; ++g) {     // 7 x 16 = 112 steps (D = 0..111)
        const int D16 = g * 16;
        #pragma unroll
        for (int k = 0; k < 8; ++k) mB[k] = ldc(crow, ib + D16 + 8 + k);
        #pragma unroll
        for (int k = 0; k < 8; ++k) pde_step(S, mA[k]);
        #pragma unroll
        for (int k = 0; k < 8; ++k) mA[k] = ldc(crow, ib + D16 + 16 + k);
        #pragma unroll
        for (int k = 0; k < 8; ++k) pde_step(S, mB[k]);
    }
    // mA holds D=112..119; tail D=120..126
    #pragma unroll
    for (int k = 0; k < 7; ++k) mB[k] = ldc(crow, ib + 120 + k);
    #pragma unroll
    for (int k = 0; k < 8; ++k) pde_step(S, mA[k]);   // D=112..119
    #pragma unroll
    for (int k = 0; k < 7; ++k) pde_step(S, mB[k]);   // D=120..126

    if (tid == 63) {
        float w = cross ? (-1.0f / 32.0f) : (1.0f / 480.0f);
        ws[bid] = w * S.b3;           // K[256][256]
    }
}

__global__ __launch_bounds__(64, 1) void sigker_reduce(
    const float* __restrict__ ws, unsigned short* __restrict__ out)
{
    const int lane = threadIdx.x;
    float s = 0.f;
    for (int k = lane; k < NPAIRS; k += 64) s += ws[k];
    #pragma unroll
    for (int off = 32; off >= 1; off >>= 1) s += __shfl_xor(s, off);
    if (lane == 0) {
        // store as bf16 (round-to-nearest-even): harness reads out as uint16
        // and decodes (u<<16) as float32.
        unsigned int u = __builtin_bit_cast(unsigned int, s);
        unsigned int r = (u + 0x7FFFu + ((u >> 16) & 1u)) >> 16;
        out[0] = (unsigned short)r;
    }
}

extern "C" void kernel_launch(void* const* d_in, const int* in_sizes, int n_in,
                              void* d_out, int out_size, void* d_ws, size_t ws_size,
                              hipStream_t stream) {
    const float* gen   = (const float*)d_in[0];
    const float* realp = (const float*)d_in[1];
    // gen buffer is 16x larger than real; robust to element- or byte-units.
    if (n_in >= 2 && in_sizes[0] < in_sizes[1]) {
        gen   = (const float*)d_in[1];
        realp = (const float*)d_in[0];
    }
    float* ws  = (float*)d_ws;
    unsigned short* out = (unsigned short*)d_out;
    sigker_kernel<<<NPAIRS, 64, 0, stream>>>(gen, realp, ws);
    sigker_reduce<<<1, 64, 0, stream>>>(ws, out);
}